// Round 1
// 665.165 us; speedup vs baseline: 2.3976x; 2.3976x over previous
//
#include <hip/hip_runtime.h>

#define B_ 32
#define C_ 128
#define HW_ 128
#define CIN_ 64
#define COUT_ 128
#define SPATIAL (HW_ * HW_)  // 16384

typedef unsigned short u16;
typedef unsigned int u32;
typedef short s16x8 __attribute__((ext_vector_type(8)));   // 8 bf16 (4 VGPRs)
typedef float f32x16 __attribute__((ext_vector_type(16))); // 32x32 MFMA acc

// Split fp32 -> bf16 hi + bf16 lo (RNE both). x ~= hi + lo with ~2^-17 rel error.
__device__ __forceinline__ void split_bf16(float x, u16& hi, u16& lo) {
    u32 u = __float_as_uint(x);
    u32 rh = (u + 0x7FFFu + ((u >> 16) & 1u)) >> 16;
    float hf = __uint_as_float(rh << 16);
    float r = x - hf;
    u32 v = __float_as_uint(r);
    u32 rl = (v + 0x7FFFu + ((v >> 16) & 1u)) >> 16;
    hi = (u16)rh; lo = (u16)rl;
}

// ---------------------------------------------------------------------------
// Kernel 1: per-(b,c) spatial sum, double accumulation (unchanged).
// ---------------------------------------------------------------------------
__global__ __launch_bounds__(256) void k_chansum(const float* __restrict__ x,
                                                 double* __restrict__ sums) {
    int bc = blockIdx.x;
    const float4* p4 = (const float4*)(x + (size_t)bc * SPATIAL);
    int t = threadIdx.x;
    double s = 0.0;
#pragma unroll
    for (int i = 0; i < 16; ++i) {
        float4 v = p4[t + 256 * i];
        s += (double)v.x + (double)v.y + (double)v.z + (double)v.w;
    }
#pragma unroll
    for (int off = 32; off > 0; off >>= 1) s += __shfl_down(s, off, 64);
    __shared__ double wsum[4];
    if ((t & 63) == 0) wsum[t >> 6] = s;
    __syncthreads();
    if (t == 0) sums[bc] = wsum[0] + wsum[1] + wsum[2] + wsum[3];
}

// ---------------------------------------------------------------------------
// Kernel 2: stable argsort-by-rank, keep first CIN_ ranks (unchanged).
// ---------------------------------------------------------------------------
__global__ __launch_bounds__(128) void k_select(const double* __restrict__ sums,
                                                int* __restrict__ idx) {
    int b = blockIdx.x, c = threadIdx.x;
    __shared__ double s[C_];
    double my = sums[b * C_ + c];
    s[c] = my;
    __syncthreads();
    int rank = 0;
    for (int j = 0; j < C_; ++j) {
        double v = s[j];
        rank += (v < my || (v == my && j < c)) ? 1 : 0;
    }
    if (rank < CIN_) idx[b * CIN_ + rank] = c;
}

// ---------------------------------------------------------------------------
// Kernel 3: weight prep — scatter w[Cout][Cin][3][3] f32 into A-fragment order
// for v_mfma_f32_32x32x16_bf16, hi and lo bf16 planes.
// Layout: wf[(((hl*9 + tap)*4 + ks)*4 + cot)*512 + lane*8 + e]
//   co = cot*32 + (lane&31); ci = ks*16 + (lane>>5)*8 + e.  288 KB, L2-hot.
// ---------------------------------------------------------------------------
__global__ __launch_bounds__(256) void k_wprep(const float* __restrict__ w,
                                               u16* __restrict__ wf) {
    int bid = blockIdx.x;            // 0..287 = hl*144 + tap*16 + ks*4 + cot
    int hl = bid / 144, rem = bid % 144;
    int tap = rem / 16, r2 = rem % 16;
    int ks = r2 / 4, cot = r2 % 4;
    int dh = tap / 3, dw = tap % 3;
    for (int j = threadIdx.x; j < 512; j += 256) {
        int lane = j >> 3, e = j & 7;
        int co = cot * 32 + (lane & 31);
        int ci = ks * 16 + (lane >> 5) * 8 + e;
        float v = w[((co * CIN_ + ci) * 3 + dh) * 3 + dw];
        u16 h, l; split_bf16(v, h, l);
        wf[(size_t)bid * 512 + j] = hl ? l : h;
    }
}

// ---------------------------------------------------------------------------
// Kernel 4: implicit-GEMM conv via bf16 MFMA, split-bf16 3-pass for fp32 acc.
// Block: 256 thr (4 waves) = all 128 Cout x (8 rows x 32 w).
//   wave wv: co-group g = wv&1 (64 co), row-group rg = wv>>1 (4 rows).
//   wave tiles: 2 co-tiles(32) x 4 row-tiles(1x32 w) of 32x32 MFMA; acc=128 VGPR.
// LDS: x tile [10 rows][34 w][32 ci] bf16 hi+lo, channel-last, staged per
//   ci-half with on-the-fly gather+split. 16B slots XOR-swizzled by (w&3) so
//   B-frag ds_read_b128 hits all 8 bank-quads uniformly.
// K loop: 2 ci-halves x 9 taps x 2 kci = 36 MFMA-K steps; taps are barrier-free
//   shifted reads of the same LDS tile (only 4 __syncthreads total).
// ---------------------------------------------------------------------------
#define ROWS 8
#define WC 32

__global__ __launch_bounds__(256, 2) void k_conv_mfma(
    const float* __restrict__ x, const u16* __restrict__ wf,
    const float* __restrict__ bias, const int* __restrict__ idx,
    float* __restrict__ out)
{
    __shared__ __align__(16) u16 tH[10 * 34 * 32];
    __shared__ __align__(16) u16 tL[10 * 34 * 32];
    __shared__ int sidx[CIN_];

    const int b = blockIdx.z;
    const int h0 = blockIdx.y * ROWS;
    const int w0 = blockIdx.x * WC;
    const int t = threadIdx.x;
    const int lane = t & 63;
    const int wv = t >> 6;
    const int g  = wv & 1;      // co0 = g*64
    const int rg = wv >> 1;     // rows rg*4 .. rg*4+3
    const int lc = lane & 31;   // MFMA col (w position)
    const int lk = lane >> 5;   // k-group select

    if (t < CIN_) sidx[t] = idx[b * CIN_ + t];

    // acc init with bias; C/D map: col=lane&31, row=(q&3)+8*(q>>2)+4*(lane>>5)
    f32x16 acc[2][4];
#pragma unroll
    for (int ct = 0; ct < 2; ++ct)
#pragma unroll
        for (int q = 0; q < 16; ++q) {
            int row = (q & 3) + 8 * (q >> 2) + 4 * lk;
            float bv = bias[g * 64 + ct * 32 + row];
#pragma unroll
            for (int rr = 0; rr < 4; ++rr) acc[ct][rr][q] = bv;
        }

    const float* xb = x + ((size_t)b << 21);  // b * C_ * SPATIAL

    for (int ch = 0; ch < 2; ++ch) {  // ci halves of 32
        __syncthreads();              // tile free (and sidx ready on ch=0)
        // stage: 8 quads x 10 rows x 34 w; each unit = 4 ci at one (r,w)
        for (int e = t; e < 8 * 10 * 34; e += 256) {
            int w_  = e % 34;
            int tmp = e / 34;
            int r   = tmp % 10;
            int q4  = tmp / 10;                 // 0..7 -> ci_local q4*4..+3
            int gh = h0 + r - 1, gw = w0 + w_ - 1;
            bool ok = ((unsigned)gh < (unsigned)HW_) && ((unsigned)gw < (unsigned)HW_);
            int cb = ch * 32 + q4 * 4;
            int c0 = sidx[cb], c1 = sidx[cb + 1], c2 = sidx[cb + 2], c3 = sidx[cb + 3];
            float v0 = 0.f, v1 = 0.f, v2 = 0.f, v3 = 0.f;
            if (ok) {
                int off = (gh << 7) + gw;
                v0 = xb[((size_t)c0 << 14) + off];
                v1 = xb[((size_t)c1 << 14) + off];
                v2 = xb[((size_t)c2 << 14) + off];
                v3 = xb[((size_t)c3 << 14) + off];
            }
            u16 ha, la, hb, lb, hc, lcc, hd, ld;
            split_bf16(v0, ha, la); split_bf16(v1, hb, lb);
            split_bf16(v2, hc, lcc); split_bf16(v3, hd, ld);
            int slot = (q4 >> 1) ^ (w_ & 3);                    // swizzled 16B slot
            int si = (r * 34 + w_) * 32 + slot * 8 + (q4 & 1) * 4;  // ushort idx
            uint2 ph, pl;
            ph.x = (u32)ha | ((u32)hb << 16); ph.y = (u32)hc | ((u32)hd << 16);
            pl.x = (u32)la | ((u32)lb << 16); pl.y = (u32)lcc | ((u32)ld << 16);
            *(uint2*)&tH[si] = ph;
            *(uint2*)&tL[si] = pl;
        }
        __syncthreads();

#pragma unroll 1
        for (int dh = 0; dh < 3; ++dh) {
#pragma unroll 1
            for (int dw = 0; dw < 3; ++dw) {
                int tap = dh * 3 + dw;
                int wT = lc + dw;                    // 0..33
                int rbase = (rg * 4 + dh) * 34 + wT;
#pragma unroll
                for (int kci = 0; kci < 2; ++kci) {
                    int sw = ((kci * 2 + lk) ^ (wT & 3)) * 8;
                    uint4 bh[4], bl[4];
#pragma unroll
                    for (int rr = 0; rr < 4; ++rr) {
                        int a = (rbase + rr * 34) * 32 + sw;
                        bh[rr] = *(const uint4*)&tH[a];
                        bl[rr] = *(const uint4*)&tL[a];
                    }
                    int ks = ch * 2 + kci;
                    const u16* pH = wf + ((size_t)(((0 * 9 + tap) * 4 + ks) * 4 + g * 2) * 64 + lane) * 8;
                    const u16* pL = wf + ((size_t)(((1 * 9 + tap) * 4 + ks) * 4 + g * 2) * 64 + lane) * 8;
#pragma unroll
                    for (int ct = 0; ct < 2; ++ct) {
                        s16x8 ah = *(const s16x8*)(pH + ct * 512);
                        s16x8 al = *(const s16x8*)(pL + ct * 512);
#pragma unroll
                        for (int rr = 0; rr < 4; ++rr) {
                            s16x8 bhv = __builtin_bit_cast(s16x8, bh[rr]);
                            s16x8 blv = __builtin_bit_cast(s16x8, bl[rr]);
                            acc[ct][rr] = __builtin_amdgcn_mfma_f32_32x32x16_bf16(ah, bhv, acc[ct][rr], 0, 0, 0);
                            acc[ct][rr] = __builtin_amdgcn_mfma_f32_32x32x16_bf16(ah, blv, acc[ct][rr], 0, 0, 0);
                            acc[ct][rr] = __builtin_amdgcn_mfma_f32_32x32x16_bf16(al, bhv, acc[ct][rr], 0, 0, 0);
                        }
                    }
                }
            }
        }
    }

    // epilogue: D col=lane&31 -> w, row -> co; rr -> h row
    const int orow0 = h0 + rg * 4;
    size_t ob = (((size_t)(b * COUT_ + g * 64)) << 14) + ((size_t)orow0 << 7) + w0 + lc;
#pragma unroll
    for (int ct = 0; ct < 2; ++ct)
#pragma unroll
        for (int rr = 0; rr < 4; ++rr)
#pragma unroll
            for (int q = 0; q < 16; ++q) {
                int row = (q & 3) + 8 * (q >> 2) + 4 * lk;
                out[ob + (((size_t)(ct * 32 + row)) << 14) + ((size_t)rr << 7)] = acc[ct][rr][q];
            }
}

// ---------------------------------------------------------------------------
// Workspace: sums 32768 B @0, idx 8192 B @32768, wfrag 294912 B @40960
// (total ~328 KB).
// ---------------------------------------------------------------------------
extern "C" void kernel_launch(void* const* d_in, const int* in_sizes, int n_in,
                              void* d_out, int out_size, void* d_ws, size_t ws_size,
                              hipStream_t stream) {
    const float* x    = (const float*)d_in[0];
    const float* w    = (const float*)d_in[1];
    const float* bias = (const float*)d_in[2];
    float* out = (float*)d_out;

    double* sums = (double*)d_ws;
    int* idx     = (int*)((char*)d_ws + 32768);
    u16* wfrag   = (u16*)((char*)d_ws + 40960);

    k_chansum<<<B_ * C_, 256, 0, stream>>>(x, sums);
    k_select<<<B_, 128, 0, stream>>>(sums, idx);
    k_wprep<<<288, 256, 0, stream>>>(w, wfrag);

    dim3 grid(HW_ / WC, HW_ / ROWS, B_);  // (4, 16, 32) = 2048 blocks
    k_conv_mfma<<<grid, 256, 0, stream>>>(x, wfrag, bias, idx, out);
}

// Round 2
// 607.806 us; speedup vs baseline: 2.6238x; 1.0944x over previous
//
#include <hip/hip_runtime.h>

#define B_ 32
#define C_ 128
#define HW_ 128
#define CIN_ 64
#define COUT_ 128
#define SPATIAL (HW_ * HW_)  // 16384

typedef unsigned short u16;
typedef unsigned int u32;
typedef short s16x8 __attribute__((ext_vector_type(8)));   // 8 bf16 (4 VGPRs)
typedef float f32x16 __attribute__((ext_vector_type(16))); // 32x32 MFMA acc

// Split fp32 -> bf16 hi + bf16 lo (RNE both). x ~= hi + lo with ~2^-17 rel error.
__device__ __forceinline__ void split_bf16(float x, u16& hi, u16& lo) {
    u32 u = __float_as_uint(x);
    u32 rh = (u + 0x7FFFu + ((u >> 16) & 1u)) >> 16;
    float hf = __uint_as_float(rh << 16);
    float r = x - hf;
    u32 v = __float_as_uint(r);
    u32 rl = (v + 0x7FFFu + ((v >> 16) & 1u)) >> 16;
    hi = (u16)rh; lo = (u16)rl;
}

// Single RNE round fp32 -> bf16.
__device__ __forceinline__ u16 rnd_bf16(float x) {
    u32 u = __float_as_uint(x);
    return (u16)((u + 0x7FFFu + ((u >> 16) & 1u)) >> 16);
}

// ---------------------------------------------------------------------------
// Kernel 1: per-(b,c) spatial sum, double accumulation (unchanged).
// ---------------------------------------------------------------------------
__global__ __launch_bounds__(256) void k_chansum(const float* __restrict__ x,
                                                 double* __restrict__ sums) {
    int bc = blockIdx.x;
    const float4* p4 = (const float4*)(x + (size_t)bc * SPATIAL);
    int t = threadIdx.x;
    double s = 0.0;
#pragma unroll
    for (int i = 0; i < 16; ++i) {
        float4 v = p4[t + 256 * i];
        s += (double)v.x + (double)v.y + (double)v.z + (double)v.w;
    }
#pragma unroll
    for (int off = 32; off > 0; off >>= 1) s += __shfl_down(s, off, 64);
    __shared__ double wsum[4];
    if ((t & 63) == 0) wsum[t >> 6] = s;
    __syncthreads();
    if (t == 0) sums[bc] = wsum[0] + wsum[1] + wsum[2] + wsum[3];
}

// ---------------------------------------------------------------------------
// Kernel 2: stable argsort-by-rank, keep first CIN_ ranks (unchanged).
// ---------------------------------------------------------------------------
__global__ __launch_bounds__(128) void k_select(const double* __restrict__ sums,
                                                int* __restrict__ idx) {
    int b = blockIdx.x, c = threadIdx.x;
    __shared__ double s[C_];
    double my = sums[b * C_ + c];
    s[c] = my;
    __syncthreads();
    int rank = 0;
    for (int j = 0; j < C_; ++j) {
        double v = s[j];
        rank += (v < my || (v == my && j < c)) ? 1 : 0;
    }
    if (rank < CIN_) idx[b * CIN_ + rank] = c;
}

// ---------------------------------------------------------------------------
// Kernel 3: weight prep — scatter w[Cout][Cin][3][3] f32 into A-fragment order
// for v_mfma_f32_32x32x16_bf16, hi and lo bf16 planes (w exact to 2^-17).
// Layout: wf[(((hl*9 + tap)*4 + ks)*4 + cot)*512 + lane*8 + e]
//   co = cot*32 + (lane&31); ci = ks*16 + (lane>>5)*8 + e.  288 KB, L2-hot.
// ---------------------------------------------------------------------------
__global__ __launch_bounds__(256) void k_wprep(const float* __restrict__ w,
                                               u16* __restrict__ wf) {
    int bid = blockIdx.x;            // 0..287 = hl*144 + tap*16 + ks*4 + cot
    int hl = bid / 144, rem = bid % 144;
    int tap = rem / 16, r2 = rem % 16;
    int ks = r2 / 4, cot = r2 % 4;
    int dh = tap / 3, dw = tap % 3;
    for (int j = threadIdx.x; j < 512; j += 256) {
        int lane = j >> 3, e = j & 7;
        int co = cot * 32 + (lane & 31);
        int ci = ks * 16 + (lane >> 5) * 8 + e;
        float v = w[((co * CIN_ + ci) * 3 + dh) * 3 + dw];
        u16 h, l; split_bf16(v, h, l);
        wf[(size_t)bid * 512 + j] = hl ? l : h;
    }
}

// ---------------------------------------------------------------------------
// Kernel 4: implicit-GEMM conv via bf16 MFMA, 2-pass: w = wh + wl (exact),
// x rounded to one bf16 plane (error w*xl ~ 7e-4 sigma << 0.03125 budget).
// Block: 256 thr (4 waves) = all 128 Cout x (8 rows x 32 w).
// LDS: single x tile [10 r][34 w][32 ci] bf16 (21.75 KB), channel-last.
// Swizzle: 16B slot s stored/read at s ^ ((w>>1)&3); bank-quad =
//   4*(w&1) + slot -> 8 consecutive lanes hit all 8 quads (minimal, no
//   counted conflicts). Round-1 used s^(w&3) which aliased to 4 quads.
// K loop: 2 ci-halves x 9 taps x 2 kci x (2ct x 4rr x 2 planes) = 576 MFMA/thr.
// ---------------------------------------------------------------------------
#define ROWS 8
#define WC 32

__global__ __launch_bounds__(256, 2) void k_conv_mfma(
    const float* __restrict__ x, const u16* __restrict__ wf,
    const float* __restrict__ bias, const int* __restrict__ idx,
    float* __restrict__ out)
{
    __shared__ __align__(16) u16 tH[10 * 34 * 32];
    __shared__ int sidx[CIN_];

    const int b = blockIdx.z;
    const int h0 = blockIdx.y * ROWS;
    const int w0 = blockIdx.x * WC;
    const int t = threadIdx.x;
    const int lane = t & 63;
    const int wv = t >> 6;
    const int g  = wv & 1;      // co0 = g*64
    const int rg = wv >> 1;     // rows rg*4 .. rg*4+3
    const int lc = lane & 31;   // MFMA col (w position)
    const int lk = lane >> 5;   // k-group select

    if (t < CIN_) sidx[t] = idx[b * CIN_ + t];

    // acc init with bias; C/D map: col=lane&31, row=(q&3)+8*(q>>2)+4*(lane>>5)
    f32x16 acc[2][4];
#pragma unroll
    for (int ct = 0; ct < 2; ++ct)
#pragma unroll
        for (int q = 0; q < 16; ++q) {
            int row = (q & 3) + 8 * (q >> 2) + 4 * lk;
            float bv = bias[g * 64 + ct * 32 + row];
#pragma unroll
            for (int rr = 0; rr < 4; ++rr) acc[ct][rr][q] = bv;
        }

    const float* xb = x + ((size_t)b << 21);  // b * C_ * SPATIAL

    for (int ch = 0; ch < 2; ++ch) {  // ci halves of 32
        __syncthreads();              // tile free (and sidx ready on ch=0)
        // stage: 4 slots x 10 rows x 34 w; each unit = 8 ci at one (r,w),
        // one ds_write_b128 at swizzled slot.
        for (int e = t; e < 4 * 10 * 34; e += 256) {
            int w_  = e % 34;
            int tmp = e / 34;
            int r   = tmp % 10;
            int s   = tmp / 10;                 // 0..3 -> ci_local s*8..s*8+7
            int gh = h0 + r - 1, gw = w0 + w_ - 1;
            bool ok = ((unsigned)gh < (unsigned)HW_) && ((unsigned)gw < (unsigned)HW_);
            int cb = ch * 32 + s * 8;
            uint4 ph = {0, 0, 0, 0};
            if (ok) {
                int off = (gh << 7) + gw;
                float v0 = xb[((size_t)sidx[cb + 0] << 14) + off];
                float v1 = xb[((size_t)sidx[cb + 1] << 14) + off];
                float v2 = xb[((size_t)sidx[cb + 2] << 14) + off];
                float v3 = xb[((size_t)sidx[cb + 3] << 14) + off];
                float v4 = xb[((size_t)sidx[cb + 4] << 14) + off];
                float v5 = xb[((size_t)sidx[cb + 5] << 14) + off];
                float v6 = xb[((size_t)sidx[cb + 6] << 14) + off];
                float v7 = xb[((size_t)sidx[cb + 7] << 14) + off];
                ph.x = (u32)rnd_bf16(v0) | ((u32)rnd_bf16(v1) << 16);
                ph.y = (u32)rnd_bf16(v2) | ((u32)rnd_bf16(v3) << 16);
                ph.z = (u32)rnd_bf16(v4) | ((u32)rnd_bf16(v5) << 16);
                ph.w = (u32)rnd_bf16(v6) | ((u32)rnd_bf16(v7) << 16);
            }
            int slot = s ^ ((w_ >> 1) & 3);                  // bank-quad swizzle
            int si = (r * 34 + w_) * 32 + slot * 8;          // ushort idx, 16B aligned
            *(uint4*)&tH[si] = ph;
        }
        __syncthreads();

#pragma unroll 1
        for (int dh = 0; dh < 3; ++dh) {
#pragma unroll
            for (int dw = 0; dw < 3; ++dw) {
                int tap = dh * 3 + dw;
                int wT = lc + dw;                    // 0..33
                int rbase = (rg * 4 + dh) * 34 + wT;
#pragma unroll
                for (int kci = 0; kci < 2; ++kci) {
                    int sw = ((kci * 2 + lk) ^ ((wT >> 1) & 3)) * 8;
                    uint4 bh[4];
#pragma unroll
                    for (int rr = 0; rr < 4; ++rr) {
                        int a = (rbase + rr * 34) * 32 + sw;
                        bh[rr] = *(const uint4*)&tH[a];
                    }
                    int ks = ch * 2 + kci;
                    const u16* pH = wf + ((size_t)(((0 * 9 + tap) * 4 + ks) * 4 + g * 2) * 64 + lane) * 8;
                    const u16* pL = wf + ((size_t)(((1 * 9 + tap) * 4 + ks) * 4 + g * 2) * 64 + lane) * 8;
#pragma unroll
                    for (int ct = 0; ct < 2; ++ct) {
                        s16x8 ah = *(const s16x8*)(pH + ct * 512);
                        s16x8 al = *(const s16x8*)(pL + ct * 512);
#pragma unroll
                        for (int rr = 0; rr < 4; ++rr) {
                            s16x8 bhv = __builtin_bit_cast(s16x8, bh[rr]);
                            acc[ct][rr] = __builtin_amdgcn_mfma_f32_32x32x16_bf16(ah, bhv, acc[ct][rr], 0, 0, 0);
                            acc[ct][rr] = __builtin_amdgcn_mfma_f32_32x32x16_bf16(al, bhv, acc[ct][rr], 0, 0, 0);
                        }
                    }
                }
            }
        }
    }

    // epilogue: D col=lane&31 -> w, row -> co; rr -> h row
    const int orow0 = h0 + rg * 4;
    size_t ob = (((size_t)(b * COUT_ + g * 64)) << 14) + ((size_t)orow0 << 7) + w0 + lc;
#pragma unroll
    for (int ct = 0; ct < 2; ++ct)
#pragma unroll
        for (int rr = 0; rr < 4; ++rr)
#pragma unroll
            for (int q = 0; q < 16; ++q) {
                int row = (q & 3) + 8 * (q >> 2) + 4 * lk;
                out[ob + (((size_t)(ct * 32 + row)) << 14) + ((size_t)rr << 7)] = acc[ct][rr][q];
            }
}

// ---------------------------------------------------------------------------
// Workspace: sums 32768 B @0, idx 8192 B @32768, wfrag 294912 B @40960
// (total ~328 KB).
// ---------------------------------------------------------------------------
extern "C" void kernel_launch(void* const* d_in, const int* in_sizes, int n_in,
                              void* d_out, int out_size, void* d_ws, size_t ws_size,
                              hipStream_t stream) {
    const float* x    = (const float*)d_in[0];
    const float* w    = (const float*)d_in[1];
    const float* bias = (const float*)d_in[2];
    float* out = (float*)d_out;

    double* sums = (double*)d_ws;
    int* idx     = (int*)((char*)d_ws + 32768);
    u16* wfrag   = (u16*)((char*)d_ws + 40960);

    k_chansum<<<B_ * C_, 256, 0, stream>>>(x, sums);
    k_select<<<B_, 128, 0, stream>>>(sums, idx);
    k_wprep<<<288, 256, 0, stream>>>(w, wfrag);

    dim3 grid(HW_ / WC, HW_ / ROWS, B_);  // (4, 16, 32) = 2048 blocks
    k_conv_mfma<<<grid, 256, 0, stream>>>(x, wfrag, bias, idx, out);
}